// Round 3
// baseline (996.481 us; speedup 1.0000x reference)
//
#include <hip/hip_runtime.h>
#include <cstdint>
#include <cstddef>

#define B_ 2048
#define N_ 62
#define FIN_ 128
#define HID_ 512
#define HEADS_ 8
#define FOUT_ 64
#define LAYERS_ 3
#define M_ (B_*N_)

typedef __bf16 bf16x8 __attribute__((ext_vector_type(8)));
typedef float  f32x4  __attribute__((ext_vector_type(4)));
typedef unsigned short u16;

#define LOG2E 1.4426950408889634f

#if __has_builtin(__builtin_amdgcn_exp2f)
#define EXP2F(x) __builtin_amdgcn_exp2f(x)
#else
#define EXP2F(x) exp2f(x)
#endif
#if __has_builtin(__builtin_amdgcn_logf)
#define LOG2F(x) __builtin_amdgcn_logf(x)
#else
#define LOG2F(x) log2f(x)
#endif

static __device__ __forceinline__ u16 f2bf(float f) {
    union { float f; uint32_t u; } v; v.f = f;
    uint32_t u = v.u;
    return (u16)((u + 0x7fffu + ((u >> 16) & 1u)) >> 16);
}
static __device__ __forceinline__ float bf2f(u16 s) {
    union { uint32_t u; float f; } v; v.u = ((uint32_t)s) << 16;
    return v.f;
}
static __device__ __forceinline__ float rdlane(float v, int l) {
    union { float f; int i; } a, b; a.f = v;
    b.i = __builtin_amdgcn_readlane(a.i, l);
    return b.f;
}

// ---------------------------------------------------------------------------
// Pack weights:
//  wmlp_t[n][k]  (n = feature 0..511, k = 0..127), bf16
//  wgat2[l][h][80][512]: rows 0..63 = W_head^T (row d, col k),
//    row 64 = log2e * (W_head @ a1), row 65 = log2e * (W_head @ a2),
//    rows 66..79 = 0.  (f1/f2 become two extra MFMA output columns.)
// ---------------------------------------------------------------------------
__global__ __launch_bounds__(256) void repack_w(
    const float* __restrict__ Wm, const float* __restrict__ Wg,
    const float* __restrict__ ag,
    u16* __restrict__ wmlp_t, u16* __restrict__ wgat2)
{
    int idx = blockIdx.x * 256 + threadIdx.x;
    const int T1 = HID_ * FIN_;                    // 65536
    const int T2 = LAYERS_ * HEADS_ * 80 * HID_;   // 983040
    if (idx < T1) {
        int n = idx / FIN_, k = idx % FIN_;
        wmlp_t[idx] = f2bf(Wm[k * HID_ + n]);
    } else if (idx < T1 + T2) {
        int j = idx - T1;
        int lh = j / (80 * HID_);
        int r  = j % (80 * HID_);
        int n = r / HID_, k = r % HID_;
        float v;
        if (n < 64) {
            v = Wg[((size_t)lh * HID_ + k) * FOUT_ + n];
        } else if (n < 66) {
            const float* ap = ag + (size_t)lh * 128 + (n - 64) * 64;
            const float* wrow = Wg + ((size_t)lh * HID_ + k) * FOUT_;
            float s = 0.f;
            for (int d = 0; d < 64; d++) s += wrow[d] * ap[d];
            v = s * LOG2E;
        } else {
            v = 0.f;
        }
        wgat2[j] = f2bf(v);
    }
}

// ---------------------------------------------------------------------------
// adjacency -> per-row 64-bit masks + transposed (per-column) masks
// ---------------------------------------------------------------------------
__global__ __launch_bounds__(256) void build_masks(
    const int* __restrict__ adj, uint64_t* __restrict__ masks,
    uint64_t* __restrict__ masksT)
{
    __shared__ uint32_t m32[128];
    const int b = blockIdx.x, tid = threadIdx.x;
    if (tid < 128) m32[tid] = 0;
    __syncthreads();
    const int* a = adj + (size_t)b * N_ * N_;
    for (int idx = tid; idx < N_ * N_; idx += 256) {
        int i = idx / N_, j = idx % N_;
        if (a[idx] > 0) atomicOr(&m32[i * 2 + (j >> 5)], 1u << (j & 31));
    }
    __syncthreads();
    if (tid < 128) ((uint32_t*)(masks + (size_t)b * 64))[tid] = m32[tid];
    if (tid < 64) {
        int j = tid;
        uint64_t c = 0;
        for (int i = 0; i < N_; i++) {
            uint64_t bit = (m32[i * 2 + (j >> 5)] >> (j & 31)) & 1u;
            c |= bit << i;
        }
        masksT[(size_t)b * 64 + j] = c;
    }
}

// ---------------------------------------------------------------------------
// Fully fused network, one block per graph, wave = head.
// Softmax in exp2 domain; f1/f2 from projection MFMA (weight rows 64/65);
// m_j from a wave-reduce upper bound (exact: softmax is m-invariant).
// MLP and PV MFMAs operand-swapped so epilogues store packed ushort4.
// ---------------------------------------------------------------------------
#define S_IN 520     // u16 stride hin/hout [64][S_IN]
#define S_T  72      // u16 stride hT [512][S_T]
#define S_X  136     // u16 stride x-stage [64][S_X]
#define X0   28160   // u16 offset of x-stage region inside buf

__global__ __launch_bounds__(512, 4) void gat_fused(
    const float* __restrict__ x,
    const float* __restrict__ bng, const float* __restrict__ bnb,
    const float* __restrict__ bnm, const float* __restrict__ bnv,
    const u16* __restrict__ wmlp_t, const float* __restrict__ bm,
    const u16* __restrict__ wgat2,
    const uint64_t* __restrict__ masks, const uint64_t* __restrict__ masksT,
    const float* __restrict__ Wout, const float* __restrict__ bout,
    float* __restrict__ out)
{
    __shared__ __align__(16) u16 buf[36864];
    __shared__ uint64_t msk[64];
    __shared__ __align__(16) float fstat[1544];
    float* F1 = fstat;          // [8][64] f1 per (head, j)  (log2e-scaled)
    float* F2 = fstat + 512;    // [8][64] f2 per (head, i)
    float* LS = fstat + 1024;   // [8][64] m + log2(s) per (head, j)

    const int tid = threadIdx.x, b = blockIdx.x;
    const int wave = tid >> 6, lane = tid & 63;
    const int lr = lane & 15, lq = lane >> 4;
    const int w64 = wave * 64;

    // per-lane transposed column mask (bit i = adj[i][lane])
    const uint64_t cm = masksT[(size_t)b * 64 + lane];
    const uint32_t cml = (uint32_t)cm, cmh = (uint32_t)(cm >> 32);

    // ---- stage BN(x) -> xs bf16 [64][136] (rows 62,63 zero); stage msk ----
    {
        const float* xg = x + (size_t)b * N_ * FIN_;
        for (int idx = tid; idx < 2048; idx += 512) {
            int n = idx >> 5, kq = idx & 31;
            ushort4 o = {0, 0, 0, 0};
            if (n < N_) {
                float s = bng[n] * rsqrtf(bnv[n] + 1e-5f);
                float sh = bnb[n] - bnm[n] * s;
                float4 v = *(const float4*)(xg + n * FIN_ + kq * 4);
                o.x = f2bf(v.x * s + sh); o.y = f2bf(v.y * s + sh);
                o.z = f2bf(v.z * s + sh); o.w = f2bf(v.w * s + sh);
            }
            *(ushort4*)&buf[X0 + n * S_X + kq * 4] = o;
        }
        if (tid < 64) msk[tid] = (tid < N_) ? masks[(size_t)b * 64 + tid] : 0ull;
    }
    __syncthreads();

    // row masks hoisted to registers (layer-invariant)
    uint64_t mi4[4];
#pragma unroll
    for (int it = 0; it < 4; it++) mi4[it] = msk[it * 16 + lr];

    // ---- MLP (operand-swapped): C[feature][node] -> packed stores ----
    {
        f32x4 acc[4][4];
#pragma unroll
        for (int mt = 0; mt < 4; mt++)
#pragma unroll
            for (int nt = 0; nt < 4; nt++) acc[mt][nt] = (f32x4){0.f, 0.f, 0.f, 0.f};
        const int c0 = w64;
#pragma unroll
        for (int kt = 0; kt < 4; kt++) {
            int k0 = kt * 32;
            bf16x8 wf[4], xf[4];
#pragma unroll
            for (int mt = 0; mt < 4; mt++)
                wf[mt] = *(const bf16x8*)(wmlp_t + (size_t)(c0 + mt * 16 + lr) * FIN_ + k0 + lq * 8);
#pragma unroll
            for (int nt = 0; nt < 4; nt++)
                xf[nt] = *(const bf16x8*)&buf[X0 + (nt * 16 + lr) * S_X + k0 + lq * 8];
#pragma unroll
            for (int mt = 0; mt < 4; mt++)
#pragma unroll
                for (int nt = 0; nt < 4; nt++)
                    acc[mt][nt] = __builtin_amdgcn_mfma_f32_16x16x32_bf16(
                        wf[mt], xf[nt], acc[mt][nt], 0, 0, 0);
        }
        __syncthreads();   // xs reads done before hin writes overlap
        f32x4 bl[4];
#pragma unroll
        for (int mt = 0; mt < 4; mt++)
            bl[mt] = *(const f32x4*)&bm[c0 + mt * 16 + lq * 4];
#pragma unroll
        for (int mt = 0; mt < 4; mt++)
#pragma unroll
            for (int nt = 0; nt < 4; nt++) {
                int node = nt * 16 + lr;
                ushort4 pk;
                pk.x = f2bf(acc[mt][nt][0] + bl[mt][0]);
                pk.y = f2bf(acc[mt][nt][1] + bl[mt][1]);
                pk.z = f2bf(acc[mt][nt][2] + bl[mt][2]);
                pk.w = f2bf(acc[mt][nt][3] + bl[mt][3]);
                if (node < N_)
                    *(ushort4*)&buf[node * S_IN + c0 + mt * 16 + lq * 4] = pk;
            }
        // zero pad rows 62,63 in this wave's column slice
        if (lane < 16) {
            uint4 z = {0u, 0u, 0u, 0u};
            *(uint4*)&buf[(N_ + (lane >> 3)) * S_IN + c0 + (lane & 7) * 8] = z;
        }
    }
    __syncthreads();

    // ---- GAT layers ----
#pragma unroll 1
    for (int l = 0; l < LAYERS_; l++) {
        const u16* wp = wgat2 + (size_t)(l * HEADS_ + wave) * 80 * HID_;

        // projection + f-columns: [64x512] @ [512x(64+16)]
        f32x4 acc[4][5];
#pragma unroll
        for (int mt = 0; mt < 4; mt++)
#pragma unroll
            for (int nt = 0; nt < 5; nt++) acc[mt][nt] = (f32x4){0.f, 0.f, 0.f, 0.f};
#pragma unroll 4
        for (int kt = 0; kt < 16; kt++) {
            int k0 = kt * 32;
            bf16x8 af[4];
#pragma unroll
            for (int mt = 0; mt < 4; mt++)
                af[mt] = *(const bf16x8*)&buf[(mt * 16 + lr) * S_IN + k0 + lq * 8];
#pragma unroll
            for (int nt = 0; nt < 5; nt++) {
                bf16x8 bfr = *(const bf16x8*)(wp + (size_t)(nt * 16 + lr) * HID_ + k0 + lq * 8);
#pragma unroll
                for (int mt = 0; mt < 4; mt++)
                    acc[mt][nt] = __builtin_amdgcn_mfma_f32_16x16x32_bf16(
                        af[mt], bfr, acc[mt][nt], 0, 0, 0);
            }
        }

        // ---- stats (fstat only -> safe before barrier; wave-local) ----
        if (lr < 2) {
            float* Fp = lr ? F2 : F1;
#pragma unroll
            for (int mt = 0; mt < 4; mt++)
#pragma unroll
                for (int r = 0; r < 4; r++)
                    Fp[w64 + mt * 16 + lq * 4 + r] = acc[mt][4][r];
        }
        float p1 = F1[w64 + lane];
        float p2 = F2[w64 + lane];
        // m_j = leaky(max_all_i f2_i + f1_j): upper bound on all masked e,
        // exact for softmax (m-invariance). 6-step wave max.
        float pm = (lane < N_) ? p2 : -3.0e38f;
#pragma unroll
        for (int off = 32; off; off >>= 1) pm = fmaxf(pm, __shfl_xor(pm, off, 64));
        float vm = pm + p1;
        float m = fmaxf(vm, 0.2f * vm);
        // masked column sum of exp2(e - m), dual accumulators
        float s0 = 0.f, s1 = 0.f;
#pragma unroll
        for (int i = 0; i < N_; i += 2) {
            float fa = rdlane(p2, i), fb = rdlane(p2, i + 1);
            float va = fa + p1, vb = fb + p1;
            va = fmaxf(va, 0.2f * va); vb = fmaxf(vb, 0.2f * vb);
            float ea = EXP2F(va - m), eb = EXP2F(vb - m);
            uint32_t w = (i < 32) ? cml : cmh;
            s0 += ((w >> (i & 31)) & 1u) ? ea : 0.f;
            s1 += ((w >> ((i + 1) & 31)) & 1u) ? eb : 0.f;
        }
        float ssum = fmaxf(s0 + s1, 1e-35f);
        LS[w64 + lane] = m + LOG2F(ssum);   // p = exp2(e - LS)

        __syncthreads();   // (A) hin reads done -> buf becomes hT

        // transpose-store h -> hT[d][j], 8B packed (wave-local rows)
#pragma unroll
        for (int mt = 0; mt < 4; mt++)
#pragma unroll
            for (int nt = 0; nt < 4; nt++) {
                ushort4 pk;
                pk.x = f2bf(acc[mt][nt][0]); pk.y = f2bf(acc[mt][nt][1]);
                pk.z = f2bf(acc[mt][nt][2]); pk.w = f2bf(acc[mt][nt][3]);
                *(ushort4*)&buf[(w64 + nt * 16 + lr) * S_T + mt * 16 + lq * 4] = pk;
            }

        // ---- PV (operand-swapped): C[d][i] = sum_j hT[d][j] * P[i][j] ----
        f32x4 acc2[4][4];
#pragma unroll
        for (int mt = 0; mt < 4; mt++)
#pragma unroll
            for (int it = 0; it < 4; it++) acc2[mt][it] = (f32x4){0.f, 0.f, 0.f, 0.f};
        float f2v[4];
#pragma unroll
        for (int it = 0; it < 4; it++) f2v[it] = F2[w64 + it * 16 + lr];
#pragma unroll
        for (int kt = 0; kt < 2; kt++) {
            int j0 = kt * 32 + lq * 8;
            f32x4 f1a = *(const f32x4*)&F1[w64 + j0];
            f32x4 f1b = *(const f32x4*)&F1[w64 + j0 + 4];
            f32x4 la  = *(const f32x4*)&LS[w64 + j0];
            f32x4 lb  = *(const f32x4*)&LS[w64 + j0 + 4];
            bf16x8 ha[4];
#pragma unroll
            for (int mt = 0; mt < 4; mt++)
                ha[mt] = *(const bf16x8*)&buf[(w64 + mt * 16 + lr) * S_T + kt * 32 + lq * 8];
#pragma unroll
            for (int it = 0; it < 4; it++) {
                uint32_t sh = (uint32_t)(mi4[it] >> (kt * 32)) >> (lq * 8);
                bf16x8 pf;
#pragma unroll
                for (int t = 0; t < 8; t++) {
                    float f1t = t < 4 ? f1a[t] : f1b[t - 4];
                    float lst = t < 4 ? la[t]  : lb[t - 4];
                    float v = f2v[it] + f1t;
                    v = fmaxf(v, 0.2f * v);
                    float p = EXP2F(v - lst);
                    p = ((sh >> t) & 1u) ? p : 0.f;
                    pf[t] = (__bf16)p;
                }
#pragma unroll
                for (int mt = 0; mt < 4; mt++)
                    acc2[mt][it] = __builtin_amdgcn_mfma_f32_16x16x32_bf16(
                        ha[mt], pf, acc2[mt][it], 0, 0, 0);
            }
        }
        __syncthreads();   // (B) all hT reads done -> buf becomes hout

        // ---- ELU epilogue: acc2[mt][it][r] = hpT[d=mt*16+lq*4+r][i=it*16+lr]
        //      4 consecutive features per lane -> packed ushort4 stores
#pragma unroll
        for (int mt = 0; mt < 4; mt++)
#pragma unroll
            for (int it = 0; it < 4; it++) {
                int i = it * 16 + lr;
                ushort4 pk;
#pragma unroll
                for (int r = 0; r < 4; r++) {
                    float v = acc2[mt][it][r];
                    v = v > 0.f ? v : __expf(v) - 1.f;
                    ((u16*)&pk)[r] = f2bf(v);
                }
                if (i < N_)
                    *(ushort4*)&buf[i * S_IN + w64 + mt * 16 + lq * 4] = pk;
            }
        // zero pad rows 62,63 in this wave's column slice
        if (lane < 16) {
            uint4 z = {0u, 0u, 0u, 0u};
            *(uint4*)&buf[(N_ + (lane >> 3)) * S_IN + w64 + (lane & 7) * 8] = z;
        }
        __syncthreads();   // (C) hout complete
    }

    // ---- pool + logits + log_softmax ----
    {
        float s = 0.f;
#pragma unroll 2
        for (int n = 0; n < N_; n++) s += bf2f(buf[n * S_IN + tid]);
        fstat[tid] = s;
    }
    __syncthreads();
    if (tid < 192) {
        int c = tid >> 6, ln = tid & 63;
        float p = 0.f;
#pragma unroll
        for (int k = ln; k < HID_; k += 64) p += fstat[k] * Wout[k * 3 + c];
        for (int off = 32; off > 0; off >>= 1) p += __shfl_down(p, off, 64);
        if (ln == 0) fstat[1536 + c] = p + bout[c];
    }
    __syncthreads();
    if (tid == 0) {
        float l0 = fstat[1536], l1 = fstat[1537], l2 = fstat[1538];
        float mm = fmaxf(l0, fmaxf(l1, l2));
        float s = __expf(l0 - mm) + __expf(l1 - mm) + __expf(l2 - mm);
        float ls = mm + logf(s);
        out[b * 3 + 0] = l0 - ls;
        out[b * 3 + 1] = l1 - ls;
        out[b * 3 + 2] = l2 - ls;
    }
}

// ---------------------------------------------------------------------------
extern "C" void kernel_launch(void* const* d_in, const int* in_sizes, int n_in,
                              void* d_out, int out_size, void* d_ws, size_t ws_size,
                              hipStream_t stream)
{
    const float* x   = (const float*)d_in[0];
    const int*   adj = (const int*)d_in[1];
    const float* bng = (const float*)d_in[2];
    const float* bnb = (const float*)d_in[3];
    const float* bnm = (const float*)d_in[4];
    const float* bnv = (const float*)d_in[5];
    const float* Wm  = (const float*)d_in[6];
    const float* bm  = (const float*)d_in[7];
    const float* Wg  = (const float*)d_in[8];
    const float* ag  = (const float*)d_in[9];
    const float* Wo  = (const float*)d_in[10];
    const float* bo  = (const float*)d_in[11];
    float* out = (float*)d_out;

    // ws layout: masks | masksT | wmlp_t | wgat2   (~4.2 MB)
    uint64_t* masks  = (uint64_t*)d_ws;
    uint64_t* masksT = masks + (size_t)B_ * 64;
    u16* wmlp_t = (u16*)(masksT + (size_t)B_ * 64);
    u16* wgat2  = wmlp_t + (size_t)HID_ * FIN_;

    int rep_total = HID_ * FIN_ + LAYERS_ * HEADS_ * 80 * HID_;  // 1048576
    repack_w<<<(rep_total + 255) / 256, 256, 0, stream>>>(Wm, Wg, ag, wmlp_t, wgat2);
    build_masks<<<B_, 256, 0, stream>>>(adj, masks, masksT);

    gat_fused<<<B_, 512, 0, stream>>>(
        x, bng, bnb, bnm, bnv, wmlp_t, bm, wgat2,
        masks, masksT, Wo, bo, out);
}

// Round 4
// 884.335 us; speedup vs baseline: 1.1268x; 1.1268x over previous
//
#include <hip/hip_runtime.h>
#include <cstdint>
#include <cstddef>

#define B_ 2048
#define N_ 62
#define FIN_ 128
#define HID_ 512
#define HEADS_ 8
#define FOUT_ 64
#define LAYERS_ 3
#define M_ (B_*N_)

typedef __bf16 bf16x8 __attribute__((ext_vector_type(8)));
typedef float  f32x4  __attribute__((ext_vector_type(4)));
typedef unsigned short u16;

#define LOG2E 1.4426950408889634f

#if __has_builtin(__builtin_amdgcn_exp2f)
#define EXP2F(x) __builtin_amdgcn_exp2f(x)
#else
#define EXP2F(x) exp2f(x)
#endif
#if __has_builtin(__builtin_amdgcn_logf)
#define LOG2F(x) __builtin_amdgcn_logf(x)
#else
#define LOG2F(x) log2f(x)
#endif

static __device__ __forceinline__ u16 f2bf(float f) {
    union { float f; uint32_t u; } v; v.f = f;
    uint32_t u = v.u;
    return (u16)((u + 0x7fffu + ((u >> 16) & 1u)) >> 16);
}
static __device__ __forceinline__ float bf2f(u16 s) {
    union { uint32_t u; float f; } v; v.u = ((uint32_t)s) << 16;
    return v.f;
}
static __device__ __forceinline__ float rdlane(float v, int l) {
    union { float f; int i; } a, b; a.f = v;
    b.i = __builtin_amdgcn_readlane(a.i, l);
    return b.f;
}

// ---------------------------------------------------------------------------
// Pack weights:
//  wmlp_t[n][k]  (n = feature 0..511, k = 0..127), bf16
//  wgat2[l][h][80][512]: rows 0..63 = W_head^T (row d, col k),
//    row 64 = log2e * (W_head @ a1), row 65 = log2e * (W_head @ a2),
//    rows 66..79 = 0.  (f1/f2 become two extra MFMA output columns.)
// ---------------------------------------------------------------------------
__global__ __launch_bounds__(256) void repack_w(
    const float* __restrict__ Wm, const float* __restrict__ Wg,
    const float* __restrict__ ag,
    u16* __restrict__ wmlp_t, u16* __restrict__ wgat2)
{
    int idx = blockIdx.x * 256 + threadIdx.x;
    const int T1 = HID_ * FIN_;                    // 65536
    const int T2 = LAYERS_ * HEADS_ * 80 * HID_;   // 983040
    if (idx < T1) {
        int n = idx / FIN_, k = idx % FIN_;
        wmlp_t[idx] = f2bf(Wm[k * HID_ + n]);
    } else if (idx < T1 + T2) {
        int j = idx - T1;
        int lh = j / (80 * HID_);
        int r  = j % (80 * HID_);
        int n = r / HID_, k = r % HID_;
        float v;
        if (n < 64) {
            v = Wg[((size_t)lh * HID_ + k) * FOUT_ + n];
        } else if (n < 66) {
            const float* ap = ag + (size_t)lh * 128 + (n - 64) * 64;
            const float* wrow = Wg + ((size_t)lh * HID_ + k) * FOUT_;
            float s = 0.f;
            for (int d = 0; d < 64; d++) s += wrow[d] * ap[d];
            v = s * LOG2E;
        } else {
            v = 0.f;
        }
        wgat2[j] = f2bf(v);
    }
}

// ---------------------------------------------------------------------------
// adjacency -> per-row 64-bit masks + transposed (per-column) masks
// ---------------------------------------------------------------------------
__global__ __launch_bounds__(256) void build_masks(
    const int* __restrict__ adj, uint64_t* __restrict__ masks,
    uint64_t* __restrict__ masksT)
{
    __shared__ uint32_t m32[128];
    const int b = blockIdx.x, tid = threadIdx.x;
    if (tid < 128) m32[tid] = 0;
    __syncthreads();
    const int* a = adj + (size_t)b * N_ * N_;
    for (int idx = tid; idx < N_ * N_; idx += 256) {
        int i = idx / N_, j = idx % N_;
        if (a[idx] > 0) atomicOr(&m32[i * 2 + (j >> 5)], 1u << (j & 31));
    }
    __syncthreads();
    if (tid < 128) ((uint32_t*)(masks + (size_t)b * 64))[tid] = m32[tid];
    if (tid < 64) {
        int j = tid;
        uint64_t c = 0;
        for (int i = 0; i < N_; i++) {
            uint64_t bit = (m32[i * 2 + (j >> 5)] >> (j & 31)) & 1u;
            c |= bit << i;
        }
        masksT[(size_t)b * 64 + j] = c;
    }
}

// ---------------------------------------------------------------------------
// Fully fused network, one block per graph, wave = head.
// Softmax in exp2 domain; f1/f2 from projection MFMA (weight rows 64/65);
// m_j from a wave-reduce upper bound (exact: softmax is m-invariant).
// Phase order keeps acc live-range minimal (round-3 spill post-mortem):
//   proj -> F-col store (acc[][4] dies) -> bar(A) -> hT store (acc dies)
//   -> stats -> PV -> bar(B) -> ELU -> bar(C)
// ---------------------------------------------------------------------------
#define S_IN 520     // u16 stride hin/hout [64][S_IN]
#define S_T  72      // u16 stride hT [512][S_T]
#define S_X  136     // u16 stride x-stage [64][S_X]
#define X0   28160   // u16 offset of x-stage region inside buf

__global__ __launch_bounds__(512, 4) void gat_fused(
    const float* __restrict__ x,
    const float* __restrict__ bng, const float* __restrict__ bnb,
    const float* __restrict__ bnm, const float* __restrict__ bnv,
    const u16* __restrict__ wmlp_t, const float* __restrict__ bm,
    const u16* __restrict__ wgat2,
    const uint64_t* __restrict__ masks, const uint64_t* __restrict__ masksT,
    const float* __restrict__ Wout, const float* __restrict__ bout,
    float* __restrict__ out)
{
    __shared__ __align__(16) u16 buf[36864];
    __shared__ uint64_t msk[64];
    __shared__ __align__(16) float fstat[1544];
    float* F1 = fstat;          // [8][64] f1 per (head, j)  (log2e-scaled)
    float* F2 = fstat + 512;    // [8][64] f2 per (head, i)
    float* LS = fstat + 1024;   // [8][64] m + log2(s) per (head, j)

    const int tid = threadIdx.x, b = blockIdx.x;
    const int wave = tid >> 6, lane = tid & 63;
    const int lr = lane & 15, lq = lane >> 4;
    const int w64 = wave * 64;

    // per-lane transposed column mask (bit i = adj[i][lane])
    const uint64_t cm = masksT[(size_t)b * 64 + lane];
    const uint32_t cml = (uint32_t)cm, cmh = (uint32_t)(cm >> 32);

    // ---- stage BN(x) -> xs bf16 [64][136] (rows 62,63 zero); stage msk ----
    {
        const float* xg = x + (size_t)b * N_ * FIN_;
        for (int idx = tid; idx < 2048; idx += 512) {
            int n = idx >> 5, kq = idx & 31;
            ushort4 o = {0, 0, 0, 0};
            if (n < N_) {
                float s = bng[n] * rsqrtf(bnv[n] + 1e-5f);
                float sh = bnb[n] - bnm[n] * s;
                float4 v = *(const float4*)(xg + n * FIN_ + kq * 4);
                o.x = f2bf(v.x * s + sh); o.y = f2bf(v.y * s + sh);
                o.z = f2bf(v.z * s + sh); o.w = f2bf(v.w * s + sh);
            }
            *(ushort4*)&buf[X0 + n * S_X + kq * 4] = o;
        }
        if (tid < 64) msk[tid] = (tid < N_) ? masks[(size_t)b * 64 + tid] : 0ull;
    }
    __syncthreads();

    // row masks hoisted to registers (layer-invariant)
    uint64_t mi4[4];
#pragma unroll
    for (int it = 0; it < 4; it++) mi4[it] = msk[it * 16 + lr];

    // ---- MLP (operand-swapped): C[feature][node] -> packed stores ----
    {
        f32x4 acc[4][4];
#pragma unroll
        for (int mt = 0; mt < 4; mt++)
#pragma unroll
            for (int nt = 0; nt < 4; nt++) acc[mt][nt] = (f32x4){0.f, 0.f, 0.f, 0.f};
        const int c0 = w64;
#pragma unroll
        for (int kt = 0; kt < 4; kt++) {
            int k0 = kt * 32;
            bf16x8 wf[4], xf[4];
#pragma unroll
            for (int mt = 0; mt < 4; mt++)
                wf[mt] = *(const bf16x8*)(wmlp_t + (size_t)(c0 + mt * 16 + lr) * FIN_ + k0 + lq * 8);
#pragma unroll
            for (int nt = 0; nt < 4; nt++)
                xf[nt] = *(const bf16x8*)&buf[X0 + (nt * 16 + lr) * S_X + k0 + lq * 8];
#pragma unroll
            for (int mt = 0; mt < 4; mt++)
#pragma unroll
                for (int nt = 0; nt < 4; nt++)
                    acc[mt][nt] = __builtin_amdgcn_mfma_f32_16x16x32_bf16(
                        wf[mt], xf[nt], acc[mt][nt], 0, 0, 0);
        }
        __syncthreads();   // xs reads done before hin writes overlap
        f32x4 bl[4];
#pragma unroll
        for (int mt = 0; mt < 4; mt++)
            bl[mt] = *(const f32x4*)&bm[c0 + mt * 16 + lq * 4];
#pragma unroll
        for (int mt = 0; mt < 4; mt++)
#pragma unroll
            for (int nt = 0; nt < 4; nt++) {
                int node = nt * 16 + lr;
                ushort4 pk;
                pk.x = f2bf(acc[mt][nt][0] + bl[mt][0]);
                pk.y = f2bf(acc[mt][nt][1] + bl[mt][1]);
                pk.z = f2bf(acc[mt][nt][2] + bl[mt][2]);
                pk.w = f2bf(acc[mt][nt][3] + bl[mt][3]);
                if (node < N_)
                    *(ushort4*)&buf[node * S_IN + c0 + mt * 16 + lq * 4] = pk;
            }
        // zero pad rows 62,63 in this wave's column slice
        if (lane < 16) {
            uint4 z = {0u, 0u, 0u, 0u};
            *(uint4*)&buf[(N_ + (lane >> 3)) * S_IN + c0 + (lane & 7) * 8] = z;
        }
    }
    __syncthreads();

    // ---- GAT layers ----
#pragma unroll 1
    for (int l = 0; l < LAYERS_; l++) {
        const u16* wp = wgat2 + (size_t)(l * HEADS_ + wave) * 80 * HID_;

        // projection + f-columns: [64x512] @ [512x(64+16)]
        f32x4 acc[4][5];
#pragma unroll
        for (int mt = 0; mt < 4; mt++)
#pragma unroll
            for (int nt = 0; nt < 5; nt++) acc[mt][nt] = (f32x4){0.f, 0.f, 0.f, 0.f};
#pragma unroll 4
        for (int kt = 0; kt < 16; kt++) {
            int k0 = kt * 32;
            bf16x8 af[4];
#pragma unroll
            for (int mt = 0; mt < 4; mt++)
                af[mt] = *(const bf16x8*)&buf[(mt * 16 + lr) * S_IN + k0 + lq * 8];
#pragma unroll
            for (int nt = 0; nt < 5; nt++) {
                bf16x8 bfr = *(const bf16x8*)(wp + (size_t)(nt * 16 + lr) * HID_ + k0 + lq * 8);
#pragma unroll
                for (int mt = 0; mt < 4; mt++)
                    acc[mt][nt] = __builtin_amdgcn_mfma_f32_16x16x32_bf16(
                        af[mt], bfr, acc[mt][nt], 0, 0, 0);
            }
        }

        // f-columns -> F1/F2 (fstat doesn't alias buf; wave-local).
        // acc[][4] dies here, leaving 64 regs live across barrier (A).
        if (lr < 2) {
            float* Fp = lr ? F2 : F1;
#pragma unroll
            for (int mt = 0; mt < 4; mt++)
#pragma unroll
                for (int r = 0; r < 4; r++)
                    Fp[w64 + mt * 16 + lq * 4 + r] = acc[mt][4][r];
        }

        __syncthreads();   // (A) hin reads done -> buf becomes hT

        // transpose-store h -> hT[d][j], 8B packed (wave-local rows);
        // acc fully dead after this -> low pressure for stats phase.
#pragma unroll
        for (int mt = 0; mt < 4; mt++)
#pragma unroll
            for (int nt = 0; nt < 4; nt++) {
                ushort4 pk;
                pk.x = f2bf(acc[mt][nt][0]); pk.y = f2bf(acc[mt][nt][1]);
                pk.z = f2bf(acc[mt][nt][2]); pk.w = f2bf(acc[mt][nt][3]);
                *(ushort4*)&buf[(w64 + nt * 16 + lr) * S_T + mt * 16 + lq * 4] = pk;
            }

        // ---- stats (wave-local; reads own wave's F1/F2) ----
        float p1 = F1[w64 + lane];
        float p2 = F2[w64 + lane];
        // m_j = leaky(max_all_i f2_i + f1_j): upper bound on all masked e,
        // exact for softmax (m-invariance). 6-step wave max.
        float pm = (lane < N_) ? p2 : -3.0e38f;
#pragma unroll
        for (int off = 32; off; off >>= 1) pm = fmaxf(pm, __shfl_xor(pm, off, 64));
        float vm = pm + p1;
        float m = fmaxf(vm, 0.2f * vm);
        // masked column sum of exp2(e - m), dual accumulators
        float s0 = 0.f, s1 = 0.f;
#pragma unroll
        for (int i = 0; i < N_; i += 2) {
            float fa = rdlane(p2, i), fb = rdlane(p2, i + 1);
            float va = fa + p1, vb = fb + p1;
            va = fmaxf(va, 0.2f * va); vb = fmaxf(vb, 0.2f * vb);
            float ea = EXP2F(va - m), eb = EXP2F(vb - m);
            uint32_t w = (i < 32) ? cml : cmh;
            s0 += ((w >> (i & 31)) & 1u) ? ea : 0.f;
            s1 += ((w >> ((i + 1) & 31)) & 1u) ? eb : 0.f;
        }
        float ssum = fmaxf(s0 + s1, 1e-35f);
        LS[w64 + lane] = m + LOG2F(ssum);   // p = exp2(e - LS)

        // ---- PV (operand-swapped): C[d][i] = sum_j hT[d][j] * P[i][j] ----
        f32x4 acc2[4][4];
#pragma unroll
        for (int mt = 0; mt < 4; mt++)
#pragma unroll
            for (int it = 0; it < 4; it++) acc2[mt][it] = (f32x4){0.f, 0.f, 0.f, 0.f};
        float f2v[4];
#pragma unroll
        for (int it = 0; it < 4; it++) f2v[it] = F2[w64 + it * 16 + lr];
#pragma unroll
        for (int kt = 0; kt < 2; kt++) {
            int j0 = kt * 32 + lq * 8;
            f32x4 f1a = *(const f32x4*)&F1[w64 + j0];
            f32x4 f1b = *(const f32x4*)&F1[w64 + j0 + 4];
            f32x4 la  = *(const f32x4*)&LS[w64 + j0];
            f32x4 lb  = *(const f32x4*)&LS[w64 + j0 + 4];
            bf16x8 ha[4];
#pragma unroll
            for (int mt = 0; mt < 4; mt++)
                ha[mt] = *(const bf16x8*)&buf[(w64 + mt * 16 + lr) * S_T + kt * 32 + lq * 8];
#pragma unroll
            for (int it = 0; it < 4; it++) {
                uint32_t sh = (uint32_t)(mi4[it] >> (kt * 32)) >> (lq * 8);
                bf16x8 pf;
#pragma unroll
                for (int t = 0; t < 8; t++) {
                    float f1t = t < 4 ? f1a[t] : f1b[t - 4];
                    float lst = t < 4 ? la[t]  : lb[t - 4];
                    float v = f2v[it] + f1t;
                    v = fmaxf(v, 0.2f * v);
                    float p = EXP2F(v - lst);
                    p = ((sh >> t) & 1u) ? p : 0.f;
                    pf[t] = (__bf16)p;
                }
#pragma unroll
                for (int mt = 0; mt < 4; mt++)
                    acc2[mt][it] = __builtin_amdgcn_mfma_f32_16x16x32_bf16(
                        ha[mt], pf, acc2[mt][it], 0, 0, 0);
            }
        }
        __syncthreads();   // (B) all hT reads done -> buf becomes hout

        // ---- ELU epilogue: acc2[mt][it][r] = hpT[d=mt*16+lq*4+r][i=it*16+lr]
        //      4 consecutive features per lane -> packed ushort4 stores
#pragma unroll
        for (int mt = 0; mt < 4; mt++)
#pragma unroll
            for (int it = 0; it < 4; it++) {
                int i = it * 16 + lr;
                ushort4 pk;
#pragma unroll
                for (int r = 0; r < 4; r++) {
                    float v = acc2[mt][it][r];
                    v = v > 0.f ? v : __expf(v) - 1.f;
                    ((u16*)&pk)[r] = f2bf(v);
                }
                if (i < N_)
                    *(ushort4*)&buf[i * S_IN + w64 + mt * 16 + lq * 4] = pk;
            }
        // zero pad rows 62,63 in this wave's column slice
        if (lane < 16) {
            uint4 z = {0u, 0u, 0u, 0u};
            *(uint4*)&buf[(N_ + (lane >> 3)) * S_IN + w64 + (lane & 7) * 8] = z;
        }
        __syncthreads();   // (C) hout complete
    }

    // ---- pool + logits + log_softmax ----
    {
        float s = 0.f;
#pragma unroll 2
        for (int n = 0; n < N_; n++) s += bf2f(buf[n * S_IN + tid]);
        fstat[tid] = s;
    }
    __syncthreads();
    if (tid < 192) {
        int c = tid >> 6, ln = tid & 63;
        float p = 0.f;
#pragma unroll
        for (int k = ln; k < HID_; k += 64) p += fstat[k] * Wout[k * 3 + c];
        for (int off = 32; off > 0; off >>= 1) p += __shfl_down(p, off, 64);
        if (ln == 0) fstat[1536 + c] = p + bout[c];
    }
    __syncthreads();
    if (tid == 0) {
        float l0 = fstat[1536], l1 = fstat[1537], l2 = fstat[1538];
        float mm = fmaxf(l0, fmaxf(l1, l2));
        float s = __expf(l0 - mm) + __expf(l1 - mm) + __expf(l2 - mm);
        float ls = mm + logf(s);
        out[b * 3 + 0] = l0 - ls;
        out[b * 3 + 1] = l1 - ls;
        out[b * 3 + 2] = l2 - ls;
    }
}

// ---------------------------------------------------------------------------
extern "C" void kernel_launch(void* const* d_in, const int* in_sizes, int n_in,
                              void* d_out, int out_size, void* d_ws, size_t ws_size,
                              hipStream_t stream)
{
    const float* x   = (const float*)d_in[0];
    const int*   adj = (const int*)d_in[1];
    const float* bng = (const float*)d_in[2];
    const float* bnb = (const float*)d_in[3];
    const float* bnm = (const float*)d_in[4];
    const float* bnv = (const float*)d_in[5];
    const float* Wm  = (const float*)d_in[6];
    const float* bm  = (const float*)d_in[7];
    const float* Wg  = (const float*)d_in[8];
    const float* ag  = (const float*)d_in[9];
    const float* Wo  = (const float*)d_in[10];
    const float* bo  = (const float*)d_in[11];
    float* out = (float*)d_out;

    // ws layout: masks | masksT | wmlp_t | wgat2   (~4.2 MB)
    uint64_t* masks  = (uint64_t*)d_ws;
    uint64_t* masksT = masks + (size_t)B_ * 64;
    u16* wmlp_t = (u16*)(masksT + (size_t)B_ * 64);
    u16* wgat2  = wmlp_t + (size_t)HID_ * FIN_;

    int rep_total = HID_ * FIN_ + LAYERS_ * HEADS_ * 80 * HID_;  // 1048576
    repack_w<<<(rep_total + 255) / 256, 256, 0, stream>>>(Wm, Wg, ag, wmlp_t, wgat2);
    build_masks<<<B_, 256, 0, stream>>>(adj, masks, masksT);

    gat_fused<<<B_, 512, 0, stream>>>(
        x, bng, bnb, bnm, bnv, wmlp_t, bm, wgat2,
        masks, masksT, Wo, bo, out);
}

// Round 5
// 727.771 us; speedup vs baseline: 1.3692x; 1.2151x over previous
//
#include <hip/hip_runtime.h>
#include <cstdint>
#include <cstddef>

#define B_ 2048
#define N_ 62
#define FIN_ 128
#define HID_ 512
#define HEADS_ 8
#define FOUT_ 64
#define LAYERS_ 3
#define M_ (B_*N_)

typedef __bf16 bf16x8 __attribute__((ext_vector_type(8)));
typedef float  f32x4  __attribute__((ext_vector_type(4)));
typedef unsigned short u16;

#define LOG2E 1.4426950408889634f

#if __has_builtin(__builtin_amdgcn_exp2f)
#define EXP2F(x) __builtin_amdgcn_exp2f(x)
#else
#define EXP2F(x) exp2f(x)
#endif
#if __has_builtin(__builtin_amdgcn_logf)
#define LOG2F(x) __builtin_amdgcn_logf(x)
#else
#define LOG2F(x) log2f(x)
#endif

static __device__ __forceinline__ u16 f2bf(float f) {
    union { float f; uint32_t u; } v; v.f = f;
    uint32_t u = v.u;
    return (u16)((u + 0x7fffu + ((u >> 16) & 1u)) >> 16);
}
static __device__ __forceinline__ float bf2f(u16 s) {
    union { uint32_t u; float f; } v; v.u = ((uint32_t)s) << 16;
    return v.f;
}
static __device__ __forceinline__ float rdlane(float v, int l) {
    union { float f; int i; } a, b; a.f = v;
    b.i = __builtin_amdgcn_readlane(a.i, l);
    return b.f;
}

// ---------------------------------------------------------------------------
// Pack weights:
//  wmlp_t[n][k]  (n = feature 0..511, k = 0..127), bf16
//  wgat2[l][h][80][512]: rows 0..63 = W_head^T (row d, col k),
//    row 64 = log2e * (W_head @ a1), row 65 = log2e * (W_head @ a2),
//    rows 66..79 = 0.  (f1/f2 computed by a separate small MFMA pass.)
// ---------------------------------------------------------------------------
__global__ __launch_bounds__(256) void repack_w(
    const float* __restrict__ Wm, const float* __restrict__ Wg,
    const float* __restrict__ ag,
    u16* __restrict__ wmlp_t, u16* __restrict__ wgat2)
{
    int idx = blockIdx.x * 256 + threadIdx.x;
    const int T1 = HID_ * FIN_;                    // 65536
    const int T2 = LAYERS_ * HEADS_ * 80 * HID_;   // 983040
    if (idx < T1) {
        int n = idx / FIN_, k = idx % FIN_;
        wmlp_t[idx] = f2bf(Wm[k * HID_ + n]);
    } else if (idx < T1 + T2) {
        int j = idx - T1;
        int lh = j / (80 * HID_);
        int r  = j % (80 * HID_);
        int n = r / HID_, k = r % HID_;
        float v;
        if (n < 64) {
            v = Wg[((size_t)lh * HID_ + k) * FOUT_ + n];
        } else if (n < 66) {
            const float* ap = ag + (size_t)lh * 128 + (n - 64) * 64;
            const float* wrow = Wg + ((size_t)lh * HID_ + k) * FOUT_;
            float s = 0.f;
            for (int d = 0; d < 64; d++) s += wrow[d] * ap[d];
            v = s * LOG2E;
        } else {
            v = 0.f;
        }
        wgat2[j] = f2bf(v);
    }
}

// ---------------------------------------------------------------------------
// adjacency -> per-row 64-bit masks + transposed (per-column) masks
// ---------------------------------------------------------------------------
__global__ __launch_bounds__(256) void build_masks(
    const int* __restrict__ adj, uint64_t* __restrict__ masks,
    uint64_t* __restrict__ masksT)
{
    __shared__ uint32_t m32[128];
    const int b = blockIdx.x, tid = threadIdx.x;
    if (tid < 128) m32[tid] = 0;
    __syncthreads();
    const int* a = adj + (size_t)b * N_ * N_;
    for (int idx = tid; idx < N_ * N_; idx += 256) {
        int i = idx / N_, j = idx % N_;
        if (a[idx] > 0) atomicOr(&m32[i * 2 + (j >> 5)], 1u << (j & 31));
    }
    __syncthreads();
    if (tid < 128) ((uint32_t*)(masks + (size_t)b * 64))[tid] = m32[tid];
    if (tid < 64) {
        int j = tid;
        uint64_t c = 0;
        for (int i = 0; i < N_; i++) {
            uint64_t bit = (m32[i * 2 + (j >> 5)] >> (j & 31)) & 1u;
            c |= bit << i;
        }
        masksT[(size_t)b * 64 + j] = c;
    }
}

// ---------------------------------------------------------------------------
// Fully fused network, one block per graph, wave = head.
// Register budget: __launch_bounds__(512,4) => 128 unified VGPR+AGPR/wave.
// Every phase keeps peak pressure <= ~110 (round-4 spill post-mortem):
//   f-pass (acc_f 16) -> F1/F2 -> stats -> main proj (acc 64) -> bar(A)
//   -> hT store (acc dies) -> PV build-then-consume (acc2 64 + pf 16)
//   -> bar(B) -> ELU -> bar(C)
// ---------------------------------------------------------------------------
#define S_IN 520     // u16 stride hin/hout [64][S_IN]
#define S_T  72      // u16 stride hT [512][S_T]
#define S_X  136     // u16 stride x-stage [64][S_X]
#define X0   28160   // u16 offset of x-stage region inside buf

__global__ __launch_bounds__(512, 4) void gat_fused(
    const float* __restrict__ x,
    const float* __restrict__ bng, const float* __restrict__ bnb,
    const float* __restrict__ bnm, const float* __restrict__ bnv,
    const u16* __restrict__ wmlp_t, const float* __restrict__ bm,
    const u16* __restrict__ wgat2,
    const uint64_t* __restrict__ masks, const uint64_t* __restrict__ masksT,
    const float* __restrict__ Wout, const float* __restrict__ bout,
    float* __restrict__ out)
{
    __shared__ __align__(16) u16 buf[36864];
    __shared__ uint64_t msk[64];
    __shared__ __align__(16) float fstat[1544];
    float* F1 = fstat;          // [8][64] f1 per (head, j)  (log2e-scaled)
    float* F2 = fstat + 512;    // [8][64] f2 per (head, i)
    float* LS = fstat + 1024;   // [8][64] m + log2(s) per (head, j)

    const int tid = threadIdx.x, b = blockIdx.x;
    const int wave = tid >> 6, lane = tid & 63;
    const int lr = lane & 15, lq = lane >> 4;
    const int w64 = wave * 64;

    // per-lane transposed column mask (bit i = adj[i][lane])
    const uint64_t cm = masksT[(size_t)b * 64 + lane];
    const uint32_t cml = (uint32_t)cm, cmh = (uint32_t)(cm >> 32);

    // ---- stage BN(x) -> xs bf16 [64][136] (rows 62,63 zero); stage msk ----
    {
        const float* xg = x + (size_t)b * N_ * FIN_;
        for (int idx = tid; idx < 2048; idx += 512) {
            int n = idx >> 5, kq = idx & 31;
            ushort4 o = {0, 0, 0, 0};
            if (n < N_) {
                float s = bng[n] * rsqrtf(bnv[n] + 1e-5f);
                float sh = bnb[n] - bnm[n] * s;
                float4 v = *(const float4*)(xg + n * FIN_ + kq * 4);
                o.x = f2bf(v.x * s + sh); o.y = f2bf(v.y * s + sh);
                o.z = f2bf(v.z * s + sh); o.w = f2bf(v.w * s + sh);
            }
            *(ushort4*)&buf[X0 + n * S_X + kq * 4] = o;
        }
        if (tid < 64) msk[tid] = (tid < N_) ? masks[(size_t)b * 64 + tid] : 0ull;
    }
    __syncthreads();

    // ---- MLP (operand-swapped): C[feature][node] -> packed stores ----
    {
        f32x4 acc[4][4];
#pragma unroll
        for (int mt = 0; mt < 4; mt++)
#pragma unroll
            for (int nt = 0; nt < 4; nt++) acc[mt][nt] = (f32x4){0.f, 0.f, 0.f, 0.f};
        const int c0 = w64;
#pragma unroll
        for (int kt = 0; kt < 4; kt++) {
            int k0 = kt * 32;
            bf16x8 xf[4];
#pragma unroll
            for (int nt = 0; nt < 4; nt++)
                xf[nt] = *(const bf16x8*)&buf[X0 + (nt * 16 + lr) * S_X + k0 + lq * 8];
#pragma unroll
            for (int mt = 0; mt < 4; mt++) {
                bf16x8 wf = *(const bf16x8*)(wmlp_t + (size_t)(c0 + mt * 16 + lr) * FIN_ + k0 + lq * 8);
#pragma unroll
                for (int nt = 0; nt < 4; nt++)
                    acc[mt][nt] = __builtin_amdgcn_mfma_f32_16x16x32_bf16(
                        wf, xf[nt], acc[mt][nt], 0, 0, 0);
            }
        }
        __syncthreads();   // xs reads done before hin writes overlap
        f32x4 bl[4];
#pragma unroll
        for (int mt = 0; mt < 4; mt++)
            bl[mt] = *(const f32x4*)&bm[c0 + mt * 16 + lq * 4];
#pragma unroll
        for (int mt = 0; mt < 4; mt++)
#pragma unroll
            for (int nt = 0; nt < 4; nt++) {
                int node = nt * 16 + lr;
                ushort4 pk;
                pk.x = f2bf(acc[mt][nt][0] + bl[mt][0]);
                pk.y = f2bf(acc[mt][nt][1] + bl[mt][1]);
                pk.z = f2bf(acc[mt][nt][2] + bl[mt][2]);
                pk.w = f2bf(acc[mt][nt][3] + bl[mt][3]);
                if (node < N_)
                    *(ushort4*)&buf[node * S_IN + c0 + mt * 16 + lq * 4] = pk;
            }
        // zero pad rows 62,63 in this wave's column slice
        if (lane < 16) {
            uint4 z = {0u, 0u, 0u, 0u};
            *(uint4*)&buf[(N_ + (lane >> 3)) * S_IN + c0 + (lane & 7) * 8] = z;
        }
    }
    __syncthreads();

    // ---- GAT layers ----
#pragma unroll 1
    for (int l = 0; l < LAYERS_; l++) {
        const u16* wp = wgat2 + (size_t)(l * HEADS_ + wave) * 80 * HID_;

        // ---- f-pass: [64x512] @ [512x16] (wa rows 64/65); acc_f = 16 regs
        {
            f32x4 accf[4];
#pragma unroll
            for (int mt = 0; mt < 4; mt++) accf[mt] = (f32x4){0.f, 0.f, 0.f, 0.f};
#pragma unroll 4
            for (int kt = 0; kt < 16; kt++) {
                int k0 = kt * 32;
                bf16x8 bfr = *(const bf16x8*)(wp + (size_t)(64 + lr) * HID_ + k0 + lq * 8);
#pragma unroll
                for (int mt = 0; mt < 4; mt++) {
                    bf16x8 af = *(const bf16x8*)&buf[(mt * 16 + lr) * S_IN + k0 + lq * 8];
                    accf[mt] = __builtin_amdgcn_mfma_f32_16x16x32_bf16(
                        af, bfr, accf[mt], 0, 0, 0);
                }
            }
            if (lr < 2) {
                float* Fp = lr ? F2 : F1;
#pragma unroll
                for (int mt = 0; mt < 4; mt++)
#pragma unroll
                    for (int r = 0; r < 4; r++)
                        Fp[w64 + mt * 16 + lq * 4 + r] = accf[mt][r];
            }
        }

        // ---- stats (wave-local: reads own wave's F1/F2, writes own LS) ----
        {
            float p1 = F1[w64 + lane];
            float p2 = F2[w64 + lane];
            // m_j = leaky(max_all_i f2_i + f1_j): upper bound on all masked e,
            // exact for softmax (m-invariance). 6-step wave max.
            float pm = (lane < N_) ? p2 : -3.0e38f;
#pragma unroll
            for (int off = 32; off; off >>= 1) pm = fmaxf(pm, __shfl_xor(pm, off, 64));
            float vm = pm + p1;
            float m = fmaxf(vm, 0.2f * vm);
            // masked column sum of exp2(e - m), dual accumulators
            float s0 = 0.f, s1 = 0.f;
#pragma unroll
            for (int i = 0; i < N_; i += 2) {
                float fa = rdlane(p2, i), fb = rdlane(p2, i + 1);
                float va = fa + p1, vb = fb + p1;
                va = fmaxf(va, 0.2f * va); vb = fmaxf(vb, 0.2f * vb);
                float ea = EXP2F(va - m), eb = EXP2F(vb - m);
                uint32_t w = (i < 32) ? cml : cmh;
                s0 += ((w >> (i & 31)) & 1u) ? ea : 0.f;
                s1 += ((w >> ((i + 1) & 31)) & 1u) ? eb : 0.f;
            }
            float ssum = fmaxf(s0 + s1, 1e-35f);
            LS[w64 + lane] = m + LOG2F(ssum);   // p = exp2(e - LS)
        }

        // ---- main projection: h = hin @ W_head (64x512 @ 512x64) ----
        f32x4 acc[4][4];
#pragma unroll
        for (int mt = 0; mt < 4; mt++)
#pragma unroll
            for (int nt = 0; nt < 4; nt++) acc[mt][nt] = (f32x4){0.f, 0.f, 0.f, 0.f};
#pragma unroll 4
        for (int kt = 0; kt < 16; kt++) {
            int k0 = kt * 32;
            bf16x8 af[4];
#pragma unroll
            for (int mt = 0; mt < 4; mt++)
                af[mt] = *(const bf16x8*)&buf[(mt * 16 + lr) * S_IN + k0 + lq * 8];
#pragma unroll
            for (int nt = 0; nt < 4; nt++) {
                bf16x8 bfr = *(const bf16x8*)(wp + (size_t)(nt * 16 + lr) * HID_ + k0 + lq * 8);
#pragma unroll
                for (int mt = 0; mt < 4; mt++)
                    acc[mt][nt] = __builtin_amdgcn_mfma_f32_16x16x32_bf16(
                        af[mt], bfr, acc[mt][nt], 0, 0, 0);
            }
        }

        __syncthreads();   // (A) hin reads done -> buf becomes hT

        // transpose-store h -> hT[d][j], 8B packed (wave-local rows);
        // acc fully dead after this.
#pragma unroll
        for (int mt = 0; mt < 4; mt++)
#pragma unroll
            for (int nt = 0; nt < 4; nt++) {
                ushort4 pk;
                pk.x = f2bf(acc[mt][nt][0]); pk.y = f2bf(acc[mt][nt][1]);
                pk.z = f2bf(acc[mt][nt][2]); pk.w = f2bf(acc[mt][nt][3]);
                *(ushort4*)&buf[(w64 + nt * 16 + lr) * S_T + mt * 16 + lq * 4] = pk;
            }

        // ---- PV (operand-swapped): C[d][i] = sum_j hT[d][j] * P[i][j].
        //      Per kt: build all 4 pf fragments (f1/LS regs die inside),
        //      then consume with one ha at a time.
        f32x4 acc2[4][4];
#pragma unroll
        for (int mt = 0; mt < 4; mt++)
#pragma unroll
            for (int it = 0; it < 4; it++) acc2[mt][it] = (f32x4){0.f, 0.f, 0.f, 0.f};
        float f2v[4];
#pragma unroll
        for (int it = 0; it < 4; it++) f2v[it] = F2[w64 + it * 16 + lr];
#pragma unroll
        for (int kt = 0; kt < 2; kt++) {
            int j0 = kt * 32 + lq * 8;
            bf16x8 pf[4];
            {
                f32x4 f1a = *(const f32x4*)&F1[w64 + j0];
                f32x4 f1b = *(const f32x4*)&F1[w64 + j0 + 4];
                f32x4 la  = *(const f32x4*)&LS[w64 + j0];
                f32x4 lb  = *(const f32x4*)&LS[w64 + j0 + 4];
#pragma unroll
                for (int it = 0; it < 4; it++) {
                    uint64_t mi = msk[it * 16 + lr];
                    uint32_t sh = (uint32_t)(mi >> (kt * 32)) >> (lq * 8);
#pragma unroll
                    for (int t = 0; t < 8; t++) {
                        float f1t = t < 4 ? f1a[t] : f1b[t - 4];
                        float lst = t < 4 ? la[t]  : lb[t - 4];
                        float v = f2v[it] + f1t;
                        v = fmaxf(v, 0.2f * v);
                        float p = EXP2F(v - lst);
                        p = ((sh >> t) & 1u) ? p : 0.f;
                        pf[it][t] = (__bf16)p;
                    }
                }
            }
#pragma unroll
            for (int mt = 0; mt < 4; mt++) {
                bf16x8 ha = *(const bf16x8*)&buf[(w64 + mt * 16 + lr) * S_T + kt * 32 + lq * 8];
#pragma unroll
                for (int it = 0; it < 4; it++)
                    acc2[mt][it] = __builtin_amdgcn_mfma_f32_16x16x32_bf16(
                        ha, pf[it], acc2[mt][it], 0, 0, 0);
            }
        }
        __syncthreads();   // (B) all hT reads done -> buf becomes hout

        // ---- ELU epilogue: acc2[mt][it][r] = hpT[d=mt*16+lq*4+r][i=it*16+lr]
        //      4 consecutive features per lane -> packed ushort4 stores
#pragma unroll
        for (int mt = 0; mt < 4; mt++)
#pragma unroll
            for (int it = 0; it < 4; it++) {
                int i = it * 16 + lr;
                ushort4 pk;
#pragma unroll
                for (int r = 0; r < 4; r++) {
                    float v = acc2[mt][it][r];
                    v = v > 0.f ? v : __expf(v) - 1.f;
                    ((u16*)&pk)[r] = f2bf(v);
                }
                if (i < N_)
                    *(ushort4*)&buf[i * S_IN + w64 + mt * 16 + lq * 4] = pk;
            }
        // zero pad rows 62,63 in this wave's column slice
        if (lane < 16) {
            uint4 z = {0u, 0u, 0u, 0u};
            *(uint4*)&buf[(N_ + (lane >> 3)) * S_IN + w64 + (lane & 7) * 8] = z;
        }
        __syncthreads();   // (C) hout complete
    }

    // ---- pool + logits + log_softmax ----
    {
        float s = 0.f;
#pragma unroll 2
        for (int n = 0; n < N_; n++) s += bf2f(buf[n * S_IN + tid]);
        fstat[tid] = s;
    }
    __syncthreads();
    if (tid < 192) {
        int c = tid >> 6, ln = tid & 63;
        float p = 0.f;
#pragma unroll
        for (int k = ln; k < HID_; k += 64) p += fstat[k] * Wout[k * 3 + c];
        for (int off = 32; off > 0; off >>= 1) p += __shfl_down(p, off, 64);
        if (ln == 0) fstat[1536 + c] = p + bout[c];
    }
    __syncthreads();
    if (tid == 0) {
        float l0 = fstat[1536], l1 = fstat[1537], l2 = fstat[1538];
        float mm = fmaxf(l0, fmaxf(l1, l2));
        float s = __expf(l0 - mm) + __expf(l1 - mm) + __expf(l2 - mm);
        float ls = mm + logf(s);
        out[b * 3 + 0] = l0 - ls;
        out[b * 3 + 1] = l1 - ls;
        out[b * 3 + 2] = l2 - ls;
    }
}

// ---------------------------------------------------------------------------
extern "C" void kernel_launch(void* const* d_in, const int* in_sizes, int n_in,
                              void* d_out, int out_size, void* d_ws, size_t ws_size,
                              hipStream_t stream)
{
    const float* x   = (const float*)d_in[0];
    const int*   adj = (const int*)d_in[1];
    const float* bng = (const float*)d_in[2];
    const float* bnb = (const float*)d_in[3];
    const float* bnm = (const float*)d_in[4];
    const float* bnv = (const float*)d_in[5];
    const float* Wm  = (const float*)d_in[6];
    const float* bm  = (const float*)d_in[7];
    const float* Wg  = (const float*)d_in[8];
    const float* ag  = (const float*)d_in[9];
    const float* Wo  = (const float*)d_in[10];
    const float* bo  = (const float*)d_in[11];
    float* out = (float*)d_out;

    // ws layout: masks | masksT | wmlp_t | wgat2   (~4.2 MB)
    uint64_t* masks  = (uint64_t*)d_ws;
    uint64_t* masksT = masks + (size_t)B_ * 64;
    u16* wmlp_t = (u16*)(masksT + (size_t)B_ * 64);
    u16* wgat2  = wmlp_t + (size_t)HID_ * FIN_;

    int rep_total = HID_ * FIN_ + LAYERS_ * HEADS_ * 80 * HID_;  // 1048576
    repack_w<<<(rep_total + 255) / 256, 256, 0, stream>>>(Wm, Wg, ag, wmlp_t, wgat2);
    build_masks<<<B_, 256, 0, stream>>>(adj, masks, masksT);

    gat_fused<<<B_, 512, 0, stream>>>(
        x, bng, bnb, bnm, bnv, wmlp_t, bm, wgat2,
        masks, masksT, Wo, bo, out);
}